// Round 14
// baseline (241.816 us; speedup 1.0000x reference)
//
#include <hip/hip_runtime.h>

#define N_NODES 100000
#define N_EDGES 800000
#define FIN 64
#define HID 128
#define NB1 391   // ceil(N_NODES/256)
#define SRCS_CAP (N_EDGES + 3 * N_NODES)   // padded CSR capacity (pad to multiple of 4 per node)
#define GI (1024 * 256)                    // init_kernel grid threads

typedef unsigned short ushort_t;
typedef __attribute__((ext_vector_type(8))) short short8;   // 8 bf16 = 4 VGPRs (MFMA A/B frag)
typedef __attribute__((ext_vector_type(16))) float fx16;    // 32x32 MFMA C/D frag
typedef __attribute__((ext_vector_type(4))) unsigned short us4;

__device__ inline ushort_t f2bf(float f) {   // RNE fp32 -> bf16
    unsigned u = __float_as_uint(f);
    u += 0x7fffu + ((u >> 16) & 1u);
    return (ushort_t)(u >> 16);
}

__device__ inline void upadd(float* acc, uint4 A) {   // accumulate 8 bf16 of a 16B chunk
    acc[0] += __uint_as_float(A.x << 16);
    acc[1] += __uint_as_float(A.x & 0xffff0000u);
    acc[2] += __uint_as_float(A.y << 16);
    acc[3] += __uint_as_float(A.y & 0xffff0000u);
    acc[4] += __uint_as_float(A.z << 16);
    acc[5] += __uint_as_float(A.z & 0xffff0000u);
    acc[6] += __uint_as_float(A.w << 16);
    acc[7] += __uint_as_float(A.w & 0xffff0000u);
}

// ------- init: zero deg + sentinel srcs + cvt x/W1 + fused layer2 weights + detect -------
// Folded-weight algebra (layer2 has no activation before the head):
//   M1 = Wfc1@W2rel (20x128), M2 = Wfc1@W2root, cb = Wfc1@b2 + bfc1.
// Mb rows: [0..20) = M1, [20..32) = 0, [32..52) = M2, [52..64) = 0.
// Detect is the PROVEN device probe — do NOT replace with in_sizes heuristics (r8/r9).
__global__ __launch_bounds__(256) void init_kernel(
    const int* __restrict__ ei, const float* __restrict__ x,
    const float* __restrict__ W1rel, const float* __restrict__ W1root,
    const float* __restrict__ W2rel, const float* __restrict__ W2root,
    const float* __restrict__ b2, const float* __restrict__ Wfc1,
    const float* __restrict__ bfc1, const float* __restrict__ Wfc2,
    int* __restrict__ deg, int* __restrict__ flag, int* __restrict__ srcs,
    ushort_t* __restrict__ xb, ushort_t* __restrict__ Wb1,
    ushort_t* __restrict__ Mb, float* __restrict__ cbp, float* __restrict__ w2p) {
    __shared__ int s[256];
    int t = threadIdx.x;
    int gtid = blockIdx.x * 256 + t;

    if (gtid < N_NODES) deg[gtid] = 0;
    for (int k = gtid; k < SRCS_CAP; k += GI) srcs[k] = N_NODES;
    for (int i = gtid; i < N_NODES * FIN / 4; i += GI) {
        float4 v = ((const float4*)x)[i];
        us4 o = {f2bf(v.x), f2bf(v.y), f2bf(v.z), f2bf(v.w)};
        ((us4*)xb)[i] = o;
    }
    us4 z = {0, 0, 0, 0};
    if (gtid < 16) ((us4*)xb)[(size_t)N_NODES * 16 + gtid] = z;   // xb zero row
    if (gtid < HID * HID) {
        int n = gtid >> 7, k = gtid & 127;
        float v = (k < FIN) ? W1rel[n * FIN + k] : W1root[n * FIN + (k - FIN)];
        Wb1[gtid] = f2bf(v);
    }
    // fused layer2 weights: blocks 0..31 compute Mb (8192 outputs, 1/thread)
    if (blockIdx.x < 32) {
        int idx = blockIdx.x * 256 + t;     // 0..8191
        int n = idx >> 7, k = idx & 127;
        float acc = 0.f;
        if (n < 20) {
            for (int j = 0; j < HID; j++) acc += Wfc1[n * HID + j] * W2rel[j * HID + k];
        } else if (n >= 32 && n < 52) {
            int m = n - 32;
            for (int j = 0; j < HID; j++) acc += Wfc1[m * HID + j] * W2root[j * HID + k];
        }
        Mb[idx] = f2bf(acc);
    }
    if (blockIdx.x == 32 && t < 32) {
        float cv = 0.f, wv = 0.f;
        if (t < 20) {
            for (int j = 0; j < HID; j++) cv += Wfc1[t * HID + j] * b2[j];
            cv += bfc1[t];
            wv = Wfc2[t];
        }
        cbp[t] = cv;
        w2p[t] = wv;
    }
    if (blockIdx.x == 33) {          // int64 little-endian => odd words all 0
        int bad = 0;
        for (int i = t; i < 8192; i += 256) bad |= ei[2 * i + 1];
        s[t] = bad;
        __syncthreads();
        for (int d = 128; d > 0; d >>= 1) {
            if (t < d) s[t] |= s[t + d];
            __syncthreads();
        }
        if (t == 0) *flag = (s[0] != 0) ? 1 : 0;   // 1 => int32 layout
    }
}

// ---------------- CSR build (padded to multiple of 4 per node; no rank array) ----------------
__global__ void hist_kernel(const int* __restrict__ w, const int* __restrict__ flag,
                            int* __restrict__ deg) {
    int e = blockIdx.x * 256 + threadIdx.x;
    if (e >= N_EDGES) return;
    int is32 = *flag;
    int d = is32 ? w[N_EDGES + e] : w[2 * (N_EDGES + e)];
    atomicAdd(&deg[d], 1);
}

__global__ void scan1_kernel(const int* __restrict__ deg, int* __restrict__ off,
                             int* __restrict__ bsums) {
    __shared__ int s[256];
    int t = threadIdx.x;
    int i = blockIdx.x * 256 + t;
    int v = (i < N_NODES) ? ((deg[i] + 3) & ~3) : 0;   // padded degree (x4)
    s[t] = v;
    __syncthreads();
    for (int d = 1; d < 256; d <<= 1) {
        int w = (t >= d) ? s[t - d] : 0;
        __syncthreads();
        s[t] += w;
        __syncthreads();
    }
    if (i < N_NODES) off[i] = s[t] - v;
    if (t == 255) bsums[blockIdx.x] = s[255];
}

// scan2+scan3 merged: block b re-derives its prefix by summing bsums[0..b).
// Also writes cursor copy for rank-free scatter.
__global__ void scan23_kernel(int* __restrict__ off, const int* __restrict__ bsums,
                              int* __restrict__ cur) {
    __shared__ int s[256];
    int t = threadIdx.x, b = blockIdx.x;
    int pre = 0, tot = 0;
    for (int j = t; j < NB1; j += 256) {
        int v = bsums[j];
        if (j < b) pre += v;
        tot += v;
    }
    s[t] = pre;
    __syncthreads();
    for (int d = 128; d > 0; d >>= 1) {
        if (t < d) s[t] += s[t + d];
        __syncthreads();
    }
    int prefix = s[0];
    __syncthreads();
    int i = b * 256 + t;
    if (i < N_NODES) {
        int v = off[i] + prefix;
        off[i] = v;
        cur[i] = v;
    }
    if (b == 0) {
        s[t] = tot;
        __syncthreads();
        for (int d = 128; d > 0; d >>= 1) {
            if (t < d) s[t] += s[t + d];
            __syncthreads();
        }
        if (t == 0) off[N_NODES] = s[0];   // total padded edge count
    }
}

// rank-free scatter: claim slot via cursor atomic (order already nondeterministic via hist)
__global__ void scatter_kernel(const int* __restrict__ w, const int* __restrict__ flag,
                               int* __restrict__ cur, int* __restrict__ srcs) {
    int e = blockIdx.x * 256 + threadIdx.x;
    if (e >= N_EDGES) return;
    int is32 = *flag;
    int s = is32 ? w[e] : w[2 * e];
    int d = is32 ? w[N_EDGES + e] : w[2 * (N_EDGES + e)];
    int pos = atomicAdd(&cur[d], 1);
    srcs[pos] = s;
}

// ------- agg1: 8 nodes/wave x 8 lanes x 16B (full 128B row). Pad x4 => maskless -------
__global__ void agg1_kernel(const ushort_t* __restrict__ xb, const int* __restrict__ off,
                            const int* __restrict__ srcs, ushort_t* __restrict__ aggb) {
    int wid = (blockIdx.x * 256 + threadIdx.x) >> 6;   // wave id
    int lane = threadIdx.x & 63;
    int n = lane >> 3;                       // node sub 0..7
    unsigned c = lane & 7;                   // 16B chunk of the 128B row
    int node = wid * 8 + n;                  // exact: 100000 = 8 * 12500 waves
    int b = off[node], e = off[node + 1];
    float acc[8];
#pragma unroll
    for (int j = 0; j < 8; j++) acc[j] = 0.f;
    const uint4* rows = (const uint4*)xb;    // 8 chunks per row (incl. zero row N)
    for (int p = b; p < e; p += 4) {
        int4 s = *(const int4*)(srcs + p);   // p is 4-aligned (pad x4), srcs base 256B-aligned
        uint4 A = rows[(unsigned)s.x * 8u + c];
        uint4 B = rows[(unsigned)s.y * 8u + c];
        uint4 C = rows[(unsigned)s.z * 8u + c];
        uint4 D = rows[(unsigned)s.w * 8u + c];
        upadd(acc, A);
        upadd(acc, B);
        upadd(acc, C);
        upadd(acc, D);
    }
    uint4 o = {(unsigned)f2bf(acc[0]) | ((unsigned)f2bf(acc[1]) << 16),
               (unsigned)f2bf(acc[2]) | ((unsigned)f2bf(acc[3]) << 16),
               (unsigned)f2bf(acc[4]) | ((unsigned)f2bf(acc[5]) << 16),
               (unsigned)f2bf(acc[6]) | ((unsigned)f2bf(acc[7]) << 16)};
    ((uint4*)(aggb + (size_t)node * FIN))[c] = o;   // 8 lanes = full row
}

// ------- fused g1+g2: h1 never touches global memory -------
// g1: h1 = elu([agg1,x]@Wb1^T + b1) -> LDS tile (reuses Wb1 region, XOR-swizzled)
// g2: uv = h1 @ Mb^T  (cols 0..31 u-part, 32..63 v-part)
// LDS 48 KB: [0..16384) Wb1 then h1 tile; [16384..24576) Mb. 3 blocks/CU.
// Tail waves (nb >= N) keep running for barriers; global writes guarded.
__global__ __launch_bounds__(256) void g12_kernel(
    const ushort_t* __restrict__ aggb, const ushort_t* __restrict__ xb,
    const ushort_t* __restrict__ Wb1, const float* __restrict__ b1,
    const ushort_t* __restrict__ Mb, ushort_t* __restrict__ uvb) {
    __shared__ ushort_t smem[24576];             // 48 KB
    ushort_t* wl = smem;                         // 16384 ushorts (32 KB): Wb1 -> h1 tile
    ushort_t* ml = smem + 16384;                 // 8192 ushorts (16 KB): Mb

    us4 z = {0, 0, 0, 0};
    if (blockIdx.x == 0 && threadIdx.x < 8)      // uvb zero row (pad slots gather it)
        ((us4*)(uvb + (size_t)N_NODES * 64))[threadIdx.x] = z;

    // stage Mb (64 x 128)
#pragma unroll
    for (int it = 0; it < 4; it++) {
        int q = it * 256 + threadIdx.x;          // 0..1023
        int n = q >> 4, c = q & 15;
        short8 v = ((const short8*)Mb)[q];
        *(short8*)(ml + n * HID + ((c ^ (n & 7)) << 3)) = v;
    }
    // stage Wb1 (128 x 128)
#pragma unroll
    for (int it = 0; it < 8; it++) {
        int q = it * 256 + threadIdx.x;
        int n = q >> 4, c = q & 15;
        short8 v = ((const short8*)Wb1)[q];
        *(short8*)(wl + n * HID + ((c ^ (n & 7)) << 3)) = v;
    }
    __syncthreads();

    int wave = threadIdx.x >> 6;
    int lane = threadIdx.x & 63;
    int half = lane >> 5, col = lane & 31;
    int nb = blockIdx.x * 128 + wave * 32;
    int nA = nb + col;
    if (nA >= N_NODES) nA = N_NODES - 1;

    short8 areg[8];
#pragma unroll
    for (int s = 0; s < 4; s++)
        areg[s] = *(const short8*)(aggb + (size_t)nA * FIN + s * 16 + half * 8);
#pragma unroll
    for (int s = 4; s < 8; s++)
        areg[s] = *(const short8*)(xb + (size_t)nA * FIN + (s - 4) * 16 + half * 8);

    fx16 acc[4];
#pragma unroll
    for (int jt = 0; jt < 4; jt++)
#pragma unroll
        for (int r = 0; r < 16; r++) acc[jt][r] = 0.f;

#pragma unroll
    for (int s = 0; s < 8; s++) {
        int c = 2 * s + half;
#pragma unroll
        for (int jt = 0; jt < 4; jt++) {
            int n = jt * 32 + col;
            short8 bq = *(const short8*)(wl + n * HID + ((c ^ (n & 7)) << 3));
            acc[jt] = __builtin_amdgcn_mfma_f32_32x32x16_bf16(areg[s], bq, acc[jt], 0, 0, 0);
        }
    }
    __syncthreads();   // Wb1 dead; reuse region as h1 tile

    // epilogue g1: bias + ELU -> bf16 -> swizzled LDS tile [node_local][feature]
#pragma unroll
    for (int jt = 0; jt < 4; jt++) {
        int j = jt * 32 + col;
        float bias = b1[j];
#pragma unroll
        for (int r = 0; r < 16; r++) {
            int nl = wave * 32 + (r & 3) + 8 * (r >> 2) + 4 * half;
            float v = acc[jt][r] + bias;
            v = v > 0.f ? v : __expf(v) - 1.f;
            wl[nl * HID + (((j >> 3) ^ (nl & 7)) << 3) + (j & 7)] = f2bf(v);
        }
    }
    __syncthreads();

    // g2: A fragments from the h1 tile (same swizzle), B = Mb
    int nl2 = wave * 32 + col;
    short8 af[8];
#pragma unroll
    for (int s = 0; s < 8; s++) {
        int c = 2 * s + half;
        af[s] = *(const short8*)(wl + nl2 * HID + ((c ^ (nl2 & 7)) << 3));
    }
    fx16 uacc[2];
#pragma unroll
    for (int jt = 0; jt < 2; jt++)
#pragma unroll
        for (int r = 0; r < 16; r++) uacc[jt][r] = 0.f;

#pragma unroll
    for (int s = 0; s < 8; s++) {
        int c = 2 * s + half;
#pragma unroll
        for (int jt = 0; jt < 2; jt++) {
            int n = jt * 32 + col;
            short8 bq = *(const short8*)(ml + n * HID + ((c ^ (n & 7)) << 3));
            uacc[jt] = __builtin_amdgcn_mfma_f32_32x32x16_bf16(af[s], bq, uacc[jt], 0, 0, 0);
        }
    }
#pragma unroll
    for (int jt = 0; jt < 2; jt++) {
        int j = jt * 32 + col;
#pragma unroll
        for (int r = 0; r < 16; r++) {
            int node = nb + (r & 3) + 8 * (r >> 2) + 4 * half;
            if (node < N_NODES) uvb[(size_t)node * 64 + j] = f2bf(uacc[jt][r]);
        }
    }
}

// ------- agg3 + head: out = relu(sum_nbr(u) + v + cb) . w2 + bfc2 -------
// 16 nodes/wave x 4 lanes x 16B (u-half = 64B = 1 request/edge). Pad x4 => maskless.
__global__ void agg3h_kernel(const ushort_t* __restrict__ uvb, const int* __restrict__ off,
                             const int* __restrict__ srcs, const float* __restrict__ cbp,
                             const float* __restrict__ w2p, const float* __restrict__ bfc2,
                             float* __restrict__ out) {
    int wid = (blockIdx.x * 256 + threadIdx.x) >> 6;   // wave id
    int lane = threadIdx.x & 63;
    int n = lane >> 2;                       // node sub 0..15
    unsigned c = lane & 3;                   // 16B chunk of the 64B u-half
    int node0 = wid * 16 + n;
    int node = (node0 < N_NODES) ? node0 : N_NODES - 1;
    int b = off[node], e = off[node + 1];
    float acc[8];
#pragma unroll
    for (int j = 0; j < 8; j++) acc[j] = 0.f;
    const uint4* rows = (const uint4*)uvb;   // 8 chunks per 128B row (incl. zero row N)
    for (int p = b; p < e; p += 4) {
        int4 s = *(const int4*)(srcs + p);   // p is 4-aligned (pad x4)
        uint4 A = rows[(unsigned)s.x * 8u + c];
        uint4 B = rows[(unsigned)s.y * 8u + c];
        uint4 C = rows[(unsigned)s.z * 8u + c];
        uint4 D = rows[(unsigned)s.w * 8u + c];
        upadd(acc, A);
        upadd(acc, B);
        upadd(acc, C);
        upadd(acc, D);
    }
    // own v (second 64B half of this node's row)
    uint4 V = rows[(size_t)node * 8u + 4u + c];
    float vv[8];
    vv[0] = __uint_as_float(V.x << 16);
    vv[1] = __uint_as_float(V.x & 0xffff0000u);
    vv[2] = __uint_as_float(V.y << 16);
    vv[3] = __uint_as_float(V.y & 0xffff0000u);
    vv[4] = __uint_as_float(V.z << 16);
    vv[5] = __uint_as_float(V.z & 0xffff0000u);
    vv[6] = __uint_as_float(V.w << 16);
    vv[7] = __uint_as_float(V.w & 0xffff0000u);
    float4 cba = ((const float4*)cbp)[c * 2];
    float4 cbb = ((const float4*)cbp)[c * 2 + 1];
    float4 w2a = ((const float4*)w2p)[c * 2];
    float4 w2b = ((const float4*)w2p)[c * 2 + 1];
    float s = 0.f, a;
    a = acc[0] + vv[0] + cba.x; s += (a > 0.f ? a : 0.f) * w2a.x;
    a = acc[1] + vv[1] + cba.y; s += (a > 0.f ? a : 0.f) * w2a.y;
    a = acc[2] + vv[2] + cba.z; s += (a > 0.f ? a : 0.f) * w2a.z;
    a = acc[3] + vv[3] + cba.w; s += (a > 0.f ? a : 0.f) * w2a.w;
    a = acc[4] + vv[4] + cbb.x; s += (a > 0.f ? a : 0.f) * w2b.x;
    a = acc[5] + vv[5] + cbb.y; s += (a > 0.f ? a : 0.f) * w2b.y;
    a = acc[6] + vv[6] + cbb.z; s += (a > 0.f ? a : 0.f) * w2b.z;
    a = acc[7] + vv[7] + cbb.w; s += (a > 0.f ? a : 0.f) * w2b.w;
    s += __shfl_xor(s, 1);
    s += __shfl_xor(s, 2);
    if (c == 0 && node0 < N_NODES) out[node0] = s + bfc2[0];
}

// ---------------- launch ----------------
extern "C" void kernel_launch(void* const* d_in, const int* in_sizes, int n_in,
                              void* d_out, int out_size, void* d_ws, size_t ws_size,
                              hipStream_t stream) {
    const float* x = (const float*)d_in[0];
    const int* ei = (const int*)d_in[1];
    const float* W1rel = (const float*)d_in[2];
    const float* b1 = (const float*)d_in[3];
    const float* W1root = (const float*)d_in[4];
    const float* W2rel = (const float*)d_in[5];
    const float* b2 = (const float*)d_in[6];
    const float* W2root = (const float*)d_in[7];
    const float* Wfc1 = (const float*)d_in[8];
    const float* bfc1 = (const float*)d_in[9];
    const float* Wfc2 = (const float*)d_in[10];
    const float* bfc2 = (const float*)d_in[11];
    float* out = (float*)d_out;

    // all offsets rounded to 256B so every buffer alignment is by construction
    char* ws = (char*)d_ws;
    size_t o = 0;
    auto alloc = [&](size_t bytes) {
        char* p = ws + o;
        o += (bytes + 255) & ~(size_t)255;
        return p;
    };
    int* deg = (int*)alloc((size_t)N_NODES * 4);
    int* off = (int*)alloc((size_t)(N_NODES + 1) * 4);
    int* bsums = (int*)alloc(4096);
    int* flag = (int*)alloc(256);
    int* cur = (int*)alloc((size_t)N_NODES * 4);                     // 0.4 MB cursor
    int* srcs = (int*)alloc((size_t)SRCS_CAP * 4);                   // 4.4 MB
    ushort_t* xb = (ushort_t*)alloc((size_t)(N_NODES + 1) * FIN * 2);   // 12.8 MB (+zero row)
    ushort_t* agg1b = (ushort_t*)alloc((size_t)N_NODES * FIN * 2);      // 12.8 MB
    ushort_t* uvb = (ushort_t*)alloc((size_t)(N_NODES + 1) * 64 * 2);   // 12.8 MB (+zero row)
    ushort_t* Wb1 = (ushort_t*)alloc((size_t)HID * HID * 2);            // 32 KB
    ushort_t* Mb = (ushort_t*)alloc((size_t)64 * HID * 2);              // 16 KB
    float* cbp = (float*)alloc(32 * 4);
    float* w2p = (float*)alloc(32 * 4);

    const int GW = (N_NODES + 127) / 128;  // 782 blocks: 4 waves x 32 nodes
    const int GA1 = N_NODES / 32;          // 3125 blocks: 4 waves x 8 nodes
    const int GA3 = 1563;                  // ceil(ceil(100000/16)/4): 4 waves x 16 nodes

    init_kernel<<<1024, 256, 0, stream>>>(ei, x, W1rel, W1root, W2rel, W2root,
                                          b2, Wfc1, bfc1, Wfc2,
                                          deg, flag, srcs, xb, Wb1, Mb, cbp, w2p);
    hist_kernel<<<(N_EDGES + 255) / 256, 256, 0, stream>>>(ei, flag, deg);
    scan1_kernel<<<NB1, 256, 0, stream>>>(deg, off, bsums);
    scan23_kernel<<<NB1, 256, 0, stream>>>(off, bsums, cur);
    scatter_kernel<<<(N_EDGES + 255) / 256, 256, 0, stream>>>(ei, flag, cur, srcs);
    agg1_kernel<<<GA1, 256, 0, stream>>>(xb, off, srcs, agg1b);
    g12_kernel<<<GW, 256, 0, stream>>>(agg1b, xb, Wb1, b1, Mb, uvb);
    agg3h_kernel<<<GA3, 256, 0, stream>>>(uvb, off, srcs, cbp, w2p, bfc2, out);
}

// Round 15
// 202.942 us; speedup vs baseline: 1.1916x; 1.1916x over previous
//
#include <hip/hip_runtime.h>

#define N_NODES 100000
#define N_EDGES 800000
#define FIN 64
#define HID 128
#define NB1 391   // ceil(N_NODES/256)
#define SRCS_CAP (N_EDGES + 3 * N_NODES)   // padded CSR capacity (pad to multiple of 4 per node)
#define GI (1024 * 256)                    // init_kernel grid threads

typedef unsigned short ushort_t;
typedef __attribute__((ext_vector_type(8))) short short8;   // 8 bf16 = 4 VGPRs (MFMA A/B frag)
typedef __attribute__((ext_vector_type(16))) float fx16;    // 32x32 MFMA C/D frag
typedef __attribute__((ext_vector_type(4))) unsigned short us4;

__device__ inline ushort_t f2bf(float f) {   // RNE fp32 -> bf16
    unsigned u = __float_as_uint(f);
    u += 0x7fffu + ((u >> 16) & 1u);
    return (ushort_t)(u >> 16);
}

__device__ inline void upadd(float* acc, uint4 A) {   // accumulate 8 bf16 of a 16B chunk
    acc[0] += __uint_as_float(A.x << 16);
    acc[1] += __uint_as_float(A.x & 0xffff0000u);
    acc[2] += __uint_as_float(A.y << 16);
    acc[3] += __uint_as_float(A.y & 0xffff0000u);
    acc[4] += __uint_as_float(A.z << 16);
    acc[5] += __uint_as_float(A.z & 0xffff0000u);
    acc[6] += __uint_as_float(A.w << 16);
    acc[7] += __uint_as_float(A.w & 0xffff0000u);
}

// ------- init: zero deg + sentinel srcs + cvt x/W1 + fused layer2 weights + detect -------
// Folded-weight algebra (layer2 has no activation before the head):
//   M1 = Wfc1@W2rel (20x128), M2 = Wfc1@W2root, cb = Wfc1@b2 + bfc1.
// Mb rows: [0..20) = M1, [20..32) = 0, [32..52) = M2, [52..64) = 0.
// Detect is the PROVEN device probe — do NOT replace with in_sizes heuristics (r8/r9).
__global__ __launch_bounds__(256) void init_kernel(
    const int* __restrict__ ei, const float* __restrict__ x,
    const float* __restrict__ W1rel, const float* __restrict__ W1root,
    const float* __restrict__ W2rel, const float* __restrict__ W2root,
    const float* __restrict__ b2, const float* __restrict__ Wfc1,
    const float* __restrict__ bfc1, const float* __restrict__ Wfc2,
    int* __restrict__ deg, int* __restrict__ flag, int* __restrict__ srcs,
    ushort_t* __restrict__ xb, ushort_t* __restrict__ Wb1,
    ushort_t* __restrict__ Mb, float* __restrict__ cbp, float* __restrict__ w2p) {
    __shared__ int s[256];
    int t = threadIdx.x;
    int gtid = blockIdx.x * 256 + t;

    if (gtid < N_NODES) deg[gtid] = 0;
    for (int k = gtid; k < SRCS_CAP; k += GI) srcs[k] = N_NODES;
    for (int i = gtid; i < N_NODES * FIN / 4; i += GI) {
        float4 v = ((const float4*)x)[i];
        us4 o = {f2bf(v.x), f2bf(v.y), f2bf(v.z), f2bf(v.w)};
        ((us4*)xb)[i] = o;
    }
    us4 z = {0, 0, 0, 0};
    if (gtid < 16) ((us4*)xb)[(size_t)N_NODES * 16 + gtid] = z;   // xb zero row
    if (gtid < HID * HID) {
        int n = gtid >> 7, k = gtid & 127;
        float v = (k < FIN) ? W1rel[n * FIN + k] : W1root[n * FIN + (k - FIN)];
        Wb1[gtid] = f2bf(v);
    }
    // fused layer2 weights: blocks 0..31 compute Mb (8192 outputs, 1/thread)
    if (blockIdx.x < 32) {
        int idx = blockIdx.x * 256 + t;     // 0..8191
        int n = idx >> 7, k = idx & 127;
        float acc = 0.f;
        if (n < 20) {
            for (int j = 0; j < HID; j++) acc += Wfc1[n * HID + j] * W2rel[j * HID + k];
        } else if (n >= 32 && n < 52) {
            int m = n - 32;
            for (int j = 0; j < HID; j++) acc += Wfc1[m * HID + j] * W2root[j * HID + k];
        }
        Mb[idx] = f2bf(acc);
    }
    if (blockIdx.x == 32 && t < 32) {
        float cv = 0.f, wv = 0.f;
        if (t < 20) {
            for (int j = 0; j < HID; j++) cv += Wfc1[t * HID + j] * b2[j];
            cv += bfc1[t];
            wv = Wfc2[t];
        }
        cbp[t] = cv;
        w2p[t] = wv;
    }
    if (blockIdx.x == 33) {          // int64 little-endian => odd words all 0
        int bad = 0;
        for (int i = t; i < 8192; i += 256) bad |= ei[2 * i + 1];
        s[t] = bad;
        __syncthreads();
        for (int d = 128; d > 0; d >>= 1) {
            if (t < d) s[t] |= s[t + d];
            __syncthreads();
        }
        if (t == 0) *flag = (s[0] != 0) ? 1 : 0;   // 1 => int32 layout
    }
}

// ---------------- CSR build (padded to multiple of 4 per node) ----------------
// hist/rank + scatter split is PROVEN (r14: cursor-atomic scatter = +35us —
// returning atomic on the store's critical path serializes on contended nodes).
__global__ void hist_kernel(const int* __restrict__ w, const int* __restrict__ flag,
                            int* __restrict__ deg, int* __restrict__ rank) {
    int e = blockIdx.x * 256 + threadIdx.x;
    if (e >= N_EDGES) return;
    int is32 = *flag;
    int d = is32 ? w[N_EDGES + e] : w[2 * (N_EDGES + e)];
    rank[e] = atomicAdd(&deg[d], 1);
}

__global__ void scan1_kernel(const int* __restrict__ deg, int* __restrict__ off,
                             int* __restrict__ bsums) {
    __shared__ int s[256];
    int t = threadIdx.x;
    int i = blockIdx.x * 256 + t;
    int v = (i < N_NODES) ? ((deg[i] + 3) & ~3) : 0;   // padded degree (x4)
    s[t] = v;
    __syncthreads();
    for (int d = 1; d < 256; d <<= 1) {
        int w = (t >= d) ? s[t - d] : 0;
        __syncthreads();
        s[t] += w;
        __syncthreads();
    }
    if (i < N_NODES) off[i] = s[t] - v;
    if (t == 255) bsums[blockIdx.x] = s[255];
}

// scan2+scan3 merged: block b re-derives its prefix by summing bsums[0..b).
__global__ void scan23_kernel(int* __restrict__ off, const int* __restrict__ bsums) {
    __shared__ int s[256];
    int t = threadIdx.x, b = blockIdx.x;
    int pre = 0, tot = 0;
    for (int j = t; j < NB1; j += 256) {
        int v = bsums[j];
        if (j < b) pre += v;
        tot += v;
    }
    s[t] = pre;
    __syncthreads();
    for (int d = 128; d > 0; d >>= 1) {
        if (t < d) s[t] += s[t + d];
        __syncthreads();
    }
    int prefix = s[0];
    __syncthreads();
    int i = b * 256 + t;
    if (i < N_NODES) off[i] += prefix;
    if (b == 0) {
        s[t] = tot;
        __syncthreads();
        for (int d = 128; d > 0; d >>= 1) {
            if (t < d) s[t] += s[t + d];
            __syncthreads();
        }
        if (t == 0) off[N_NODES] = s[0];   // total padded edge count
    }
}

__global__ void scatter_kernel(const int* __restrict__ w, const int* __restrict__ flag,
                               const int* __restrict__ off, const int* __restrict__ rank,
                               int* __restrict__ srcs) {
    int e = blockIdx.x * 256 + threadIdx.x;
    if (e >= N_EDGES) return;
    int is32 = *flag;
    int s = is32 ? w[e] : w[2 * e];
    int d = is32 ? w[N_EDGES + e] : w[2 * (N_EDGES + e)];
    srcs[off[d] + rank[e]] = s;
}

// ------- agg1: 8 nodes/wave x 8 lanes x 16B (full 128B row). Pad x4 => maskless -------
__global__ void agg1_kernel(const ushort_t* __restrict__ xb, const int* __restrict__ off,
                            const int* __restrict__ srcs, ushort_t* __restrict__ aggb) {
    int wid = (blockIdx.x * 256 + threadIdx.x) >> 6;   // wave id
    int lane = threadIdx.x & 63;
    int n = lane >> 3;                       // node sub 0..7
    unsigned c = lane & 7;                   // 16B chunk of the 128B row
    int node = wid * 8 + n;                  // exact: 100000 = 8 * 12500 waves
    int b = off[node], e = off[node + 1];
    float acc[8];
#pragma unroll
    for (int j = 0; j < 8; j++) acc[j] = 0.f;
    const uint4* rows = (const uint4*)xb;    // 8 chunks per row (incl. zero row N)
    for (int p = b; p < e; p += 4) {
        int4 s = *(const int4*)(srcs + p);   // p is 4-aligned (pad x4), srcs base 256B-aligned
        uint4 A = rows[(unsigned)s.x * 8u + c];
        uint4 B = rows[(unsigned)s.y * 8u + c];
        uint4 C = rows[(unsigned)s.z * 8u + c];
        uint4 D = rows[(unsigned)s.w * 8u + c];
        upadd(acc, A);
        upadd(acc, B);
        upadd(acc, C);
        upadd(acc, D);
    }
    uint4 o = {(unsigned)f2bf(acc[0]) | ((unsigned)f2bf(acc[1]) << 16),
               (unsigned)f2bf(acc[2]) | ((unsigned)f2bf(acc[3]) << 16),
               (unsigned)f2bf(acc[4]) | ((unsigned)f2bf(acc[5]) << 16),
               (unsigned)f2bf(acc[6]) | ((unsigned)f2bf(acc[7]) << 16)};
    ((uint4*)(aggb + (size_t)node * FIN))[c] = o;   // 8 lanes = full row
}

// ------- fused g1+g2: h1 never touches global memory -------
// g1: h1 = elu([agg1,x]@Wb1^T + b1) -> LDS tile (reuses Wb1 region, XOR-swizzled)
// g2: uv = h1 @ Mb^T  (cols 0..31 u-part, 32..63 v-part)
// LDS 48 KB: [0..16384) Wb1 then h1 tile; [16384..24576) Mb. 3 blocks/CU.
// Tail waves (nb >= N) keep running for barriers; global writes guarded.
__global__ __launch_bounds__(256) void g12_kernel(
    const ushort_t* __restrict__ aggb, const ushort_t* __restrict__ xb,
    const ushort_t* __restrict__ Wb1, const float* __restrict__ b1,
    const ushort_t* __restrict__ Mb, ushort_t* __restrict__ uvb) {
    __shared__ ushort_t smem[24576];             // 48 KB
    ushort_t* wl = smem;                         // 16384 ushorts (32 KB): Wb1 -> h1 tile
    ushort_t* ml = smem + 16384;                 // 8192 ushorts (16 KB): Mb

    us4 z = {0, 0, 0, 0};
    if (blockIdx.x == 0 && threadIdx.x < 8)      // uvb zero row (pad slots gather it)
        ((us4*)(uvb + (size_t)N_NODES * 64))[threadIdx.x] = z;

    // stage Mb (64 x 128)
#pragma unroll
    for (int it = 0; it < 4; it++) {
        int q = it * 256 + threadIdx.x;          // 0..1023
        int n = q >> 4, c = q & 15;
        short8 v = ((const short8*)Mb)[q];
        *(short8*)(ml + n * HID + ((c ^ (n & 7)) << 3)) = v;
    }
    // stage Wb1 (128 x 128)
#pragma unroll
    for (int it = 0; it < 8; it++) {
        int q = it * 256 + threadIdx.x;
        int n = q >> 4, c = q & 15;
        short8 v = ((const short8*)Wb1)[q];
        *(short8*)(wl + n * HID + ((c ^ (n & 7)) << 3)) = v;
    }
    __syncthreads();

    int wave = threadIdx.x >> 6;
    int lane = threadIdx.x & 63;
    int half = lane >> 5, col = lane & 31;
    int nb = blockIdx.x * 128 + wave * 32;
    int nA = nb + col;
    if (nA >= N_NODES) nA = N_NODES - 1;

    short8 areg[8];
#pragma unroll
    for (int s = 0; s < 4; s++)
        areg[s] = *(const short8*)(aggb + (size_t)nA * FIN + s * 16 + half * 8);
#pragma unroll
    for (int s = 4; s < 8; s++)
        areg[s] = *(const short8*)(xb + (size_t)nA * FIN + (s - 4) * 16 + half * 8);

    fx16 acc[4];
#pragma unroll
    for (int jt = 0; jt < 4; jt++)
#pragma unroll
        for (int r = 0; r < 16; r++) acc[jt][r] = 0.f;

#pragma unroll
    for (int s = 0; s < 8; s++) {
        int c = 2 * s + half;
#pragma unroll
        for (int jt = 0; jt < 4; jt++) {
            int n = jt * 32 + col;
            short8 bq = *(const short8*)(wl + n * HID + ((c ^ (n & 7)) << 3));
            acc[jt] = __builtin_amdgcn_mfma_f32_32x32x16_bf16(areg[s], bq, acc[jt], 0, 0, 0);
        }
    }
    __syncthreads();   // Wb1 dead; reuse region as h1 tile

    // epilogue g1: bias + ELU -> bf16 -> swizzled LDS tile [node_local][feature]
#pragma unroll
    for (int jt = 0; jt < 4; jt++) {
        int j = jt * 32 + col;
        float bias = b1[j];
#pragma unroll
        for (int r = 0; r < 16; r++) {
            int nl = wave * 32 + (r & 3) + 8 * (r >> 2) + 4 * half;
            float v = acc[jt][r] + bias;
            v = v > 0.f ? v : __expf(v) - 1.f;
            wl[nl * HID + (((j >> 3) ^ (nl & 7)) << 3) + (j & 7)] = f2bf(v);
        }
    }
    __syncthreads();

    // g2: A fragments from the h1 tile (same swizzle), B = Mb
    int nl2 = wave * 32 + col;
    short8 af[8];
#pragma unroll
    for (int s = 0; s < 8; s++) {
        int c = 2 * s + half;
        af[s] = *(const short8*)(wl + nl2 * HID + ((c ^ (nl2 & 7)) << 3));
    }
    fx16 uacc[2];
#pragma unroll
    for (int jt = 0; jt < 2; jt++)
#pragma unroll
        for (int r = 0; r < 16; r++) uacc[jt][r] = 0.f;

#pragma unroll
    for (int s = 0; s < 8; s++) {
        int c = 2 * s + half;
#pragma unroll
        for (int jt = 0; jt < 2; jt++) {
            int n = jt * 32 + col;
            short8 bq = *(const short8*)(ml + n * HID + ((c ^ (n & 7)) << 3));
            uacc[jt] = __builtin_amdgcn_mfma_f32_32x32x16_bf16(af[s], bq, uacc[jt], 0, 0, 0);
        }
    }
#pragma unroll
    for (int jt = 0; jt < 2; jt++) {
        int j = jt * 32 + col;
#pragma unroll
        for (int r = 0; r < 16; r++) {
            int node = nb + (r & 3) + 8 * (r >> 2) + 4 * half;
            if (node < N_NODES) uvb[(size_t)node * 64 + j] = f2bf(uacc[jt][r]);
        }
    }
}

// ------- agg3 + head: out = relu(sum_nbr(u) + v + cb) . w2 + bfc2 -------
// 16 nodes/wave x 4 lanes x 16B (u-half = 64B = 1 request/edge). Pad x4 => maskless.
__global__ void agg3h_kernel(const ushort_t* __restrict__ uvb, const int* __restrict__ off,
                             const int* __restrict__ srcs, const float* __restrict__ cbp,
                             const float* __restrict__ w2p, const float* __restrict__ bfc2,
                             float* __restrict__ out) {
    int wid = (blockIdx.x * 256 + threadIdx.x) >> 6;   // wave id
    int lane = threadIdx.x & 63;
    int n = lane >> 2;                       // node sub 0..15
    unsigned c = lane & 3;                   // 16B chunk of the 64B u-half
    int node0 = wid * 16 + n;
    int node = (node0 < N_NODES) ? node0 : N_NODES - 1;
    int b = off[node], e = off[node + 1];
    float acc[8];
#pragma unroll
    for (int j = 0; j < 8; j++) acc[j] = 0.f;
    const uint4* rows = (const uint4*)uvb;   // 8 chunks per 128B row (incl. zero row N)
    for (int p = b; p < e; p += 4) {
        int4 s = *(const int4*)(srcs + p);   // p is 4-aligned (pad x4)
        uint4 A = rows[(unsigned)s.x * 8u + c];
        uint4 B = rows[(unsigned)s.y * 8u + c];
        uint4 C = rows[(unsigned)s.z * 8u + c];
        uint4 D = rows[(unsigned)s.w * 8u + c];
        upadd(acc, A);
        upadd(acc, B);
        upadd(acc, C);
        upadd(acc, D);
    }
    // own v (second 64B half of this node's row)
    uint4 V = rows[(size_t)node * 8u + 4u + c];
    float vv[8];
    vv[0] = __uint_as_float(V.x << 16);
    vv[1] = __uint_as_float(V.x & 0xffff0000u);
    vv[2] = __uint_as_float(V.y << 16);
    vv[3] = __uint_as_float(V.y & 0xffff0000u);
    vv[4] = __uint_as_float(V.z << 16);
    vv[5] = __uint_as_float(V.z & 0xffff0000u);
    vv[6] = __uint_as_float(V.w << 16);
    vv[7] = __uint_as_float(V.w & 0xffff0000u);
    float4 cba = ((const float4*)cbp)[c * 2];
    float4 cbb = ((const float4*)cbp)[c * 2 + 1];
    float4 w2a = ((const float4*)w2p)[c * 2];
    float4 w2b = ((const float4*)w2p)[c * 2 + 1];
    float s = 0.f, a;
    a = acc[0] + vv[0] + cba.x; s += (a > 0.f ? a : 0.f) * w2a.x;
    a = acc[1] + vv[1] + cba.y; s += (a > 0.f ? a : 0.f) * w2a.y;
    a = acc[2] + vv[2] + cba.z; s += (a > 0.f ? a : 0.f) * w2a.z;
    a = acc[3] + vv[3] + cba.w; s += (a > 0.f ? a : 0.f) * w2a.w;
    a = acc[4] + vv[4] + cbb.x; s += (a > 0.f ? a : 0.f) * w2b.x;
    a = acc[5] + vv[5] + cbb.y; s += (a > 0.f ? a : 0.f) * w2b.y;
    a = acc[6] + vv[6] + cbb.z; s += (a > 0.f ? a : 0.f) * w2b.z;
    a = acc[7] + vv[7] + cbb.w; s += (a > 0.f ? a : 0.f) * w2b.w;
    s += __shfl_xor(s, 1);
    s += __shfl_xor(s, 2);
    if (c == 0 && node0 < N_NODES) out[node0] = s + bfc2[0];
}

// ---------------- launch ----------------
extern "C" void kernel_launch(void* const* d_in, const int* in_sizes, int n_in,
                              void* d_out, int out_size, void* d_ws, size_t ws_size,
                              hipStream_t stream) {
    const float* x = (const float*)d_in[0];
    const int* ei = (const int*)d_in[1];
    const float* W1rel = (const float*)d_in[2];
    const float* b1 = (const float*)d_in[3];
    const float* W1root = (const float*)d_in[4];
    const float* W2rel = (const float*)d_in[5];
    const float* b2 = (const float*)d_in[6];
    const float* W2root = (const float*)d_in[7];
    const float* Wfc1 = (const float*)d_in[8];
    const float* bfc1 = (const float*)d_in[9];
    const float* Wfc2 = (const float*)d_in[10];
    const float* bfc2 = (const float*)d_in[11];
    float* out = (float*)d_out;

    // all offsets rounded to 256B so every buffer alignment is by construction
    char* ws = (char*)d_ws;
    size_t o = 0;
    auto alloc = [&](size_t bytes) {
        char* p = ws + o;
        o += (bytes + 255) & ~(size_t)255;
        return p;
    };
    int* deg = (int*)alloc((size_t)N_NODES * 4);
    int* off = (int*)alloc((size_t)(N_NODES + 1) * 4);
    int* bsums = (int*)alloc(4096);
    int* flag = (int*)alloc(256);
    int* rank = (int*)alloc((size_t)N_EDGES * 4);                    // 3.2 MB
    int* srcs = (int*)alloc((size_t)SRCS_CAP * 4);                   // 4.4 MB
    ushort_t* xb = (ushort_t*)alloc((size_t)(N_NODES + 1) * FIN * 2);   // 12.8 MB (+zero row)
    ushort_t* agg1b = (ushort_t*)alloc((size_t)N_NODES * FIN * 2);      // 12.8 MB
    ushort_t* uvb = (ushort_t*)alloc((size_t)(N_NODES + 1) * 64 * 2);   // 12.8 MB (+zero row)
    ushort_t* Wb1 = (ushort_t*)alloc((size_t)HID * HID * 2);            // 32 KB
    ushort_t* Mb = (ushort_t*)alloc((size_t)64 * HID * 2);              // 16 KB
    float* cbp = (float*)alloc(32 * 4);
    float* w2p = (float*)alloc(32 * 4);

    const int GW = (N_NODES + 127) / 128;  // 782 blocks: 4 waves x 32 nodes
    const int GA1 = N_NODES / 32;          // 3125 blocks: 4 waves x 8 nodes
    const int GA3 = 1563;                  // ceil(ceil(100000/16)/4): 4 waves x 16 nodes

    init_kernel<<<1024, 256, 0, stream>>>(ei, x, W1rel, W1root, W2rel, W2root,
                                          b2, Wfc1, bfc1, Wfc2,
                                          deg, flag, srcs, xb, Wb1, Mb, cbp, w2p);
    hist_kernel<<<(N_EDGES + 255) / 256, 256, 0, stream>>>(ei, flag, deg, rank);
    scan1_kernel<<<NB1, 256, 0, stream>>>(deg, off, bsums);
    scan23_kernel<<<NB1, 256, 0, stream>>>(off, bsums);
    scatter_kernel<<<(N_EDGES + 255) / 256, 256, 0, stream>>>(ei, flag, off, rank, srcs);
    agg1_kernel<<<GA1, 256, 0, stream>>>(xb, off, srcs, agg1b);
    g12_kernel<<<GW, 256, 0, stream>>>(agg1b, xb, Wb1, b1, Mb, uvb);
    agg3h_kernel<<<GA3, 256, 0, stream>>>(uvb, off, srcs, cbp, w2p, bfc2, out);
}